// Round 7
// baseline (127.249 us; speedup 1.0000x reference)
//
#include <hip/hip_runtime.h>
#include <math.h>

// Problem constants
#define NN   768
#define HH   300
#define KD   768

// ---- ws float layout (matrices stored [h][i], 768 i per row) ----
// P:  [2 g][8 ks][320][768] gemm partials  @ 0
// CF_t[320][768] = hx^T                    @ 3932160
// AF_t[320][768] = (hy[perm]+b1)^T         @ 4177920
// SP  [4][768][768] pairwise h-partials    @ 4423680
// ES  esum[768]                            @ 9142272
// T0  t0 contributions[768]                @ 9143040
// CNT completion counter (uint)            @ 9143808
#define P_OFF    0
#define PKS_STR  245760           // 320*768
#define PG_STR   1966080          // 8*PKS_STR
#define CF_OFF   3932160
#define AF_OFF   4177920
#define SP_OFF   4423680
#define SP_STR   589824
#define ES_OFF   9142272
#define T0_OFF   9143040
#define CNT_OFF  9143808

// ========== K1: both GEMMs, transposed out, fat tile, K-split 8 =============
// P[g][ks][h][i] = sum_{k in slice} W1[h][koff+k] * src[row(i)][k]
// tile 64h x 128i, per-thread 4h x 8i (32 accs), Kc=96, 256 threads.
// grid (6 i, 5 h, 16 = g*8+ks) = 480 blocks.
__global__ __launch_bounds__(256) void k1_gemm(
    const float* __restrict__ x, const float* __restrict__ y,
    const int* __restrict__ perm, const float* __restrict__ W1,
    float* __restrict__ wsf)
{
    const int tid = threadIdx.x;
    const int tx = tid & 15;          // i: {4tx..4tx+3} u {64+4tx..}
    const int ty = tid >> 4;          // h: 4ty..4ty+3
    const int i0 = blockIdx.x * 128;
    const int h0 = blockIdx.y * 64;
    const int g  = blockIdx.z & 1;
    const int ks = blockIdx.z >> 1;
    const int kbeg = ks * 96;

    const float* src = g ? y : x;
    const int koff = g ? KD : 0;

    __shared__ float Xt[32][132];     // Xt[k][i]
    __shared__ float Wt[32][68];      // Wt[k][h]

    float4 acc[4][2];
    #pragma unroll
    for (int r = 0; r < 4; ++r) { acc[r][0] = make_float4(0,0,0,0);
                                  acc[r][1] = make_float4(0,0,0,0); }

    const int kq = (tid & 7) << 2;
    const float* xp[4];
    int xr[4];
    #pragma unroll
    for (int it = 0; it < 4; ++it) {
        int row = ((tid + it*256) >> 3);          // 0..127
        int gr = i0 + row;
        if (g) gr = perm[gr];
        xp[it] = src + (size_t)gr * KD + kbeg + kq;
        xr[it] = row;
    }
    const float* wp[2];
    int wr[2]; bool wv[2];
    #pragma unroll
    for (int it = 0; it < 2; ++it) {
        int hrow = ((tid + it*256) >> 3);         // 0..63
        int hg = h0 + hrow;
        wv[it] = hg < HH;
        wp[it] = W1 + (size_t)(wv[it] ? hg : 0) * (2*KD) + koff + kbeg + kq;
        wr[it] = hrow;
    }

    for (int kb = 0; kb < 96; kb += 32) {
        float4 xv[4], wvv[2];
        #pragma unroll
        for (int it = 0; it < 4; ++it) xv[it] = *(const float4*)(xp[it] + kb);
        #pragma unroll
        for (int it = 0; it < 2; ++it) {
            wvv[it] = *(const float4*)(wp[it] + kb);
            if (!wv[it]) wvv[it] = make_float4(0,0,0,0);
        }
        if (kb) __syncthreads();
        #pragma unroll
        for (int it = 0; it < 4; ++it) {
            Xt[kq+0][xr[it]] = xv[it].x; Xt[kq+1][xr[it]] = xv[it].y;
            Xt[kq+2][xr[it]] = xv[it].z; Xt[kq+3][xr[it]] = xv[it].w;
        }
        #pragma unroll
        for (int it = 0; it < 2; ++it) {
            Wt[kq+0][wr[it]] = wvv[it].x; Wt[kq+1][wr[it]] = wvv[it].y;
            Wt[kq+2][wr[it]] = wvv[it].z; Wt[kq+3][wr[it]] = wvv[it].w;
        }
        __syncthreads();

        #pragma unroll 8
        for (int k = 0; k < 32; ++k) {
            float4 a  = *(const float4*)&Wt[k][4*ty];
            float4 b0 = *(const float4*)&Xt[k][4*tx];
            float4 b1v = *(const float4*)&Xt[k][64 + 4*tx];
            float ar[4] = {a.x, a.y, a.z, a.w};
            #pragma unroll
            for (int r = 0; r < 4; ++r) {
                acc[r][0].x = fmaf(ar[r], b0.x,  acc[r][0].x);
                acc[r][0].y = fmaf(ar[r], b0.y,  acc[r][0].y);
                acc[r][0].z = fmaf(ar[r], b0.z,  acc[r][0].z);
                acc[r][0].w = fmaf(ar[r], b0.w,  acc[r][0].w);
                acc[r][1].x = fmaf(ar[r], b1v.x, acc[r][1].x);
                acc[r][1].y = fmaf(ar[r], b1v.y, acc[r][1].y);
                acc[r][1].z = fmaf(ar[r], b1v.z, acc[r][1].z);
                acc[r][1].w = fmaf(ar[r], b1v.w, acc[r][1].w);
            }
        }
    }

    float* dst = wsf + P_OFF + (size_t)(g*8 + ks) * PKS_STR;
    #pragma unroll
    for (int r = 0; r < 4; ++r) {
        float* rp = dst + (size_t)(h0 + 4*ty + r) * NN + i0;
        *(float4*)(rp + 4*tx)      = acc[r][0];
        *(float4*)(rp + 64 + 4*tx) = acc[r][1];
    }
}

// ===== K1b: sum 8 K-partials -> CF_t/AF_t; A += b1; pads -> 0; zero CNT =====
__global__ __launch_bounds__(256) void k1b_combine(
    const float* __restrict__ b1, float* __restrict__ wsf)
{
    int idx = blockIdx.x * 256 + threadIdx.x;   // 480 blocks -> 122880
    if (idx == 0) *(unsigned int*)(wsf + CNT_OFF) = 0u;
    int g = idx >= 61440;
    int rem = idx - g * 61440;
    int h = rem / 192;
    int i4 = (rem % 192) * 4;

    float4 o = make_float4(0.f,0.f,0.f,0.f);
    if (h < HH) {
        const float* p = wsf + P_OFF + (size_t)g * PG_STR + (size_t)h * NN + i4;
        #pragma unroll
        for (int ks = 0; ks < 8; ++ks) {
            float4 v = *(const float4*)(p + (size_t)ks * PKS_STR);
            o.x += v.x; o.y += v.y; o.z += v.z; o.w += v.w;
        }
        if (g) {
            float bv = b1[h];
            o.x += bv; o.y += bv; o.z += bv; o.w += bv;
        }
    }
    float* dst = wsf + (g ? AF_OFF : CF_OFF) + (size_t)h * NN + i4;
    *(float4*)dst = o;
}

// ======== K2: pairwise relu-dot h-partials, 4 chunks of exactly 75 ==========
// tile 48i x 96j, per-thread 3i x 6j (18 accs), grid (8 j,16 i,4 p) = 512
// blocks = exactly 2 per CU (no tail).
__global__ __launch_bounds__(256) void k2_pair(
    const float* __restrict__ wsf, const float* __restrict__ w2,
    float* __restrict__ sp)
{
    const int tid = threadIdx.x;
    const int tx = tid & 15;           // j: {4tx..4tx+3} u {64+2tx,65+2tx}
    const int ty = tid >> 4;           // i: {2ty,2ty+1} u {32+ty}
    const int j0 = blockIdx.x * 96;
    const int i0 = blockIdx.y * 48;
    const int p  = blockIdx.z;
    const int h0 = p * 75;             // 4*75 = 300 exactly

    const float* AF = wsf + AF_OFF;
    const float* CF = wsf + CF_OFF;

    __shared__ float As[75][52];       // As[h][i], 48 + pad
    __shared__ float Cs[75][100];      // Cs[h][j], 96 + pad
    __shared__ float w2s[75];

    // stage A: 75 h-rows x 12 float4 = 900 (coalesced rows of AF_t)
    for (int e = tid; e < 900; e += 256) {
        int h = e / 12, q = (e % 12) * 4;
        *(float4*)&As[h][q] = *(const float4*)(AF + (size_t)(h0 + h) * NN + i0 + q);
    }
    // stage C: 75 x 24 float4 = 1800
    for (int e = tid; e < 1800; e += 256) {
        int h = e / 24, q = (e % 24) * 4;
        *(float4*)&Cs[h][q] = *(const float4*)(CF + (size_t)(h0 + h) * NN + j0 + q);
    }
    if (tid < 75) w2s[tid] = w2[h0 + tid];
    __syncthreads();

    float acc[3][6];
    #pragma unroll
    for (int r = 0; r < 3; ++r)
        #pragma unroll
        for (int c = 0; c < 6; ++c) acc[r][c] = 0.f;

    #pragma unroll 3
    for (int h = 0; h < 75; ++h) {
        float wh = w2s[h];
        float2 a01 = *(const float2*)&As[h][2*ty];
        float  a2  = As[h][32 + ty];
        float4 c03 = *(const float4*)&Cs[h][4*tx];
        float2 c45 = *(const float2*)&Cs[h][64 + 2*tx];
        float ar[3] = {a01.x, a01.y, a2};
        float cr[6] = {c03.x, c03.y, c03.z, c03.w, c45.x, c45.y};
        #pragma unroll
        for (int r = 0; r < 3; ++r) {
            #pragma unroll
            for (int c = 0; c < 6; ++c) {
                float t = fmaxf(ar[r] + cr[c], 0.f);
                acc[r][c] = fmaf(t, wh, acc[r][c]);
            }
        }
    }

    float* dst = sp + (size_t)p * SP_STR;
    #pragma unroll
    for (int r = 0; r < 3; ++r) {
        int i = (r < 2) ? (i0 + 2*ty + r) : (i0 + 32 + ty);
        float* rp = dst + (size_t)i * NN + j0;
        *(float4*)(rp + 4*tx) =
            make_float4(acc[r][0], acc[r][1], acc[r][2], acc[r][3]);
        *(float2*)(rp + 64 + 2*tx) = make_float2(acc[r][4], acc[r][5]);
    }
}

// ==== K2e: per row: combine 4 partials, exp-rowsum; diagonal j==perm[row]
//      gives t0 (bijection). Device-scope atomic stores + completion counter;
//      last block does the final double-precision reduction. ================
__global__ __launch_bounds__(256) void k2e_rows(
    const float* __restrict__ wsf, const int* __restrict__ perm,
    const float* __restrict__ b2,
    float* __restrict__ esum, float* __restrict__ t0c,
    unsigned int* __restrict__ cnt, float* __restrict__ out)
{
    const int tid = threadIdx.x;
    const float b2v = b2[0];
    const int row = blockIdx.x;
    const int pj = perm[row];          // column holding the matched pair
    const float* spr = wsf + SP_OFF + (size_t)row * NN;
    __shared__ float red[256];
    __shared__ int last;

    float e = 0.f;
    #pragma unroll
    for (int jj = 0; jj < 3; ++jj) {
        int j = tid + jj * 256;
        float s = spr[j]
                + spr[(size_t)1 * SP_STR + j]
                + spr[(size_t)2 * SP_STR + j]
                + spr[(size_t)3 * SP_STR + j];
        float u = s + b2v;
        e += expf(u);
        if (j == pj) {                 // exactly one thread matches
            float t0 = (u > 0.f) ? u + log1pf(expf(-u)) : log1pf(expf(u));
            atomicExch(&t0c[row], t0); // device-scope store (XCD-coherent)
        }
    }
    red[tid] = e;
    __syncthreads();
    for (int s = 128; s > 0; s >>= 1) {
        if (tid < s) red[tid] += red[tid + s];
        __syncthreads();
    }
    if (tid == 0) {
        atomicExch(&esum[row], red[0]);
        __threadfence();
        unsigned int old = atomicAdd(cnt, 1u);
        last = (old == (unsigned int)(NN - 1));
    }
    __syncthreads();

    if (last) {
        __threadfence();
        double st0 = 0.0, slse = 0.0;
        for (int i = tid; i < NN; i += 256) {
            float es = atomicAdd(&esum[i], 0.f);   // coherent read
            float t0 = atomicAdd(&t0c[i],  0.f);
            slse += log((double)NN + (double)es);
            st0  += (double)t0;
        }
        __shared__ double sa[256], sb[256];
        sa[tid] = st0; sb[tid] = slse;
        __syncthreads();
        for (int s = 128; s > 0; s >>= 1) {
            if (tid < s) { sa[tid] += sa[tid+s]; sb[tid] += sb[tid+s]; }
            __syncthreads();
        }
        if (tid == 0) {
            double lb = sa[0]/(double)NN - (sb[0]/(double)NN - log((double)NN));
            out[0] = (float)lb;
        }
    }
}

extern "C" void kernel_launch(void* const* d_in, const int* in_sizes, int n_in,
                              void* d_out, int out_size, void* d_ws, size_t ws_size,
                              hipStream_t stream) {
    const float* x    = (const float*)d_in[0];
    const float* y    = (const float*)d_in[1];
    const int*   perm = (const int*)  d_in[2];
    const float* W1   = (const float*)d_in[3];
    const float* b1   = (const float*)d_in[4];
    const float* W2   = (const float*)d_in[5];
    const float* b2   = (const float*)d_in[6];
    float* wsf = (float*)d_ws;
    float* out = (float*)d_out;

    k1_gemm    <<<dim3(6,5,16),  256, 0, stream>>>(x, y, perm, W1, wsf);
    k1b_combine<<<480,           256, 0, stream>>>(b1, wsf);
    k2_pair    <<<dim3(8,16,4),  256, 0, stream>>>(wsf, W2, wsf + SP_OFF);
    k2e_rows   <<<NN,            256, 0, stream>>>(wsf, perm, b2,
                                                   wsf + ES_OFF, wsf + T0_OFF,
                                                   (unsigned int*)(wsf + CNT_OFF),
                                                   out);
}

// Round 8
// 117.603 us; speedup vs baseline: 1.0820x; 1.0820x over previous
//
#include <hip/hip_runtime.h>
#include <math.h>

// Problem constants
#define NN   768
#define HH   300
#define KD   768

// ---- ws float layout (matrices stored [h][i], 768 i per row) ----
// P:  [2 g][8 ks][320][768] gemm partials  @ 0
// CF_t[320][768] = hx^T                    @ 3932160
// AF_t[320][768] = (hy[perm]+b1)^T         @ 4177920
// SP  [8][768][768] pairwise h-partials    @ 4423680
// ES  esum[768]                            @ 9142272
// T0  t0 contributions[768]                @ 9143040
#define P_OFF    0
#define PKS_STR  245760           // 320*768
#define PG_STR   1966080          // 8*PKS_STR
#define CF_OFF   3932160
#define AF_OFF   4177920
#define SP_OFF   4423680
#define SP_STR   589824
#define ES_OFF   9142272
#define T0_OFF   9143040

// ========== K1: both GEMMs, transposed out, fat tile, K-split 8 =============
// P[g][ks][h][i] = sum_{k in slice} W1[h][koff+k] * src[row(i)][k]
// tile 64h x 128i, per-thread 4h x 8i (32 accs), Kc=96, 256 threads.
// grid (6 i, 5 h, 16 = g*8+ks) = 480 blocks.
__global__ __launch_bounds__(256) void k1_gemm(
    const float* __restrict__ x, const float* __restrict__ y,
    const int* __restrict__ perm, const float* __restrict__ W1,
    float* __restrict__ wsf)
{
    const int tid = threadIdx.x;
    const int tx = tid & 15;          // i: {4tx..4tx+3} u {64+4tx..}
    const int ty = tid >> 4;          // h: 4ty..4ty+3
    const int i0 = blockIdx.x * 128;
    const int h0 = blockIdx.y * 64;
    const int g  = blockIdx.z & 1;
    const int ks = blockIdx.z >> 1;
    const int kbeg = ks * 96;

    const float* src = g ? y : x;
    const int koff = g ? KD : 0;

    __shared__ float Xt[32][132];     // Xt[k][i]
    __shared__ float Wt[32][68];      // Wt[k][h]

    float4 acc[4][2];
    #pragma unroll
    for (int r = 0; r < 4; ++r) { acc[r][0] = make_float4(0,0,0,0);
                                  acc[r][1] = make_float4(0,0,0,0); }

    const int kq = (tid & 7) << 2;
    const float* xp[4];
    int xr[4];
    #pragma unroll
    for (int it = 0; it < 4; ++it) {
        int row = ((tid + it*256) >> 3);          // 0..127
        int gr = i0 + row;
        if (g) gr = perm[gr];
        xp[it] = src + (size_t)gr * KD + kbeg + kq;
        xr[it] = row;
    }
    const float* wp[2];
    int wr[2]; bool wv[2];
    #pragma unroll
    for (int it = 0; it < 2; ++it) {
        int hrow = ((tid + it*256) >> 3);         // 0..63
        int hg = h0 + hrow;
        wv[it] = hg < HH;
        wp[it] = W1 + (size_t)(wv[it] ? hg : 0) * (2*KD) + koff + kbeg + kq;
        wr[it] = hrow;
    }

    for (int kb = 0; kb < 96; kb += 32) {
        float4 xv[4], wvv[2];
        #pragma unroll
        for (int it = 0; it < 4; ++it) xv[it] = *(const float4*)(xp[it] + kb);
        #pragma unroll
        for (int it = 0; it < 2; ++it) {
            wvv[it] = *(const float4*)(wp[it] + kb);
            if (!wv[it]) wvv[it] = make_float4(0,0,0,0);
        }
        if (kb) __syncthreads();
        #pragma unroll
        for (int it = 0; it < 4; ++it) {
            Xt[kq+0][xr[it]] = xv[it].x; Xt[kq+1][xr[it]] = xv[it].y;
            Xt[kq+2][xr[it]] = xv[it].z; Xt[kq+3][xr[it]] = xv[it].w;
        }
        #pragma unroll
        for (int it = 0; it < 2; ++it) {
            Wt[kq+0][wr[it]] = wvv[it].x; Wt[kq+1][wr[it]] = wvv[it].y;
            Wt[kq+2][wr[it]] = wvv[it].z; Wt[kq+3][wr[it]] = wvv[it].w;
        }
        __syncthreads();

        #pragma unroll 8
        for (int k = 0; k < 32; ++k) {
            float4 a  = *(const float4*)&Wt[k][4*ty];
            float4 b0 = *(const float4*)&Xt[k][4*tx];
            float4 b1v = *(const float4*)&Xt[k][64 + 4*tx];
            float ar[4] = {a.x, a.y, a.z, a.w};
            #pragma unroll
            for (int r = 0; r < 4; ++r) {
                acc[r][0].x = fmaf(ar[r], b0.x,  acc[r][0].x);
                acc[r][0].y = fmaf(ar[r], b0.y,  acc[r][0].y);
                acc[r][0].z = fmaf(ar[r], b0.z,  acc[r][0].z);
                acc[r][0].w = fmaf(ar[r], b0.w,  acc[r][0].w);
                acc[r][1].x = fmaf(ar[r], b1v.x, acc[r][1].x);
                acc[r][1].y = fmaf(ar[r], b1v.y, acc[r][1].y);
                acc[r][1].z = fmaf(ar[r], b1v.z, acc[r][1].z);
                acc[r][1].w = fmaf(ar[r], b1v.w, acc[r][1].w);
            }
        }
    }

    float* dst = wsf + P_OFF + (size_t)(g*8 + ks) * PKS_STR;
    #pragma unroll
    for (int r = 0; r < 4; ++r) {
        float* rp = dst + (size_t)(h0 + 4*ty + r) * NN + i0;
        *(float4*)(rp + 4*tx)      = acc[r][0];
        *(float4*)(rp + 64 + 4*tx) = acc[r][1];
    }
}

// ===== K1b: sum 8 K-partials -> CF_t/AF_t; A += b1; pad h-rows -> 0 =========
__global__ __launch_bounds__(256) void k1b_combine(
    const float* __restrict__ b1, float* __restrict__ wsf)
{
    int idx = blockIdx.x * 256 + threadIdx.x;   // 480 blocks -> 122880
    int g = idx >= 61440;
    int rem = idx - g * 61440;
    int h = rem / 192;
    int i4 = (rem % 192) * 4;

    float4 o = make_float4(0.f,0.f,0.f,0.f);
    if (h < HH) {
        const float* p = wsf + P_OFF + (size_t)g * PG_STR + (size_t)h * NN + i4;
        #pragma unroll
        for (int ks = 0; ks < 8; ++ks) {
            float4 v = *(const float4*)(p + (size_t)ks * PKS_STR);
            o.x += v.x; o.y += v.y; o.z += v.z; o.w += v.w;
        }
        if (g) {
            float bv = b1[h];
            o.x += bv; o.y += bv; o.z += bv; o.w += bv;
        }
    }
    float* dst = wsf + (g ? AF_OFF : CF_OFF) + (size_t)h * NN + i4;
    *(float4*)dst = o;
}

// ======== K2: pairwise relu-dot h-partials, 8 chunks of 38 ==================
// tile 96i x 96j, per-thread 6i x 6j (36 accs), grid (8 j, 8 i, 8 p) = 512
// blocks = exactly 2/CU. Per-wave-h: 36 LDS-cyc vs 216 VALU-cyc (x4 SIMD:
// 144 < 216 => VALU-bound with margin).
__global__ __launch_bounds__(256) void k2_pair(
    const float* __restrict__ wsf, const float* __restrict__ w2,
    float* __restrict__ sp)
{
    const int tid = threadIdx.x;
    const int tx = tid & 15;           // j: {4tx..4tx+3} u {64+2tx,65+2tx}
    const int ty = tid >> 4;           // i: {4ty..4ty+3} u {64+2ty,65+2ty}
    const int j0 = blockIdx.x * 96;
    const int i0 = blockIdx.y * 96;
    const int p  = blockIdx.z;
    const int h0 = p * 38;

    const float* AF = wsf + AF_OFF;
    const float* CF = wsf + CF_OFF;

    __shared__ float As[38][100];      // As[h][i], 96 + pad
    __shared__ float Cs[38][100];      // Cs[h][j]
    __shared__ float w2s[38];

    // stage A: 38 h-rows x 24 float4 = 912 (coalesced rows of AF_t)
    for (int e = tid; e < 912; e += 256) {
        int h = e / 24, q = (e % 24) * 4;
        *(float4*)&As[h][q] = *(const float4*)(AF + (size_t)(h0 + h) * NN + i0 + q);
    }
    // stage C: 38 x 24 float4 = 912
    for (int e = tid; e < 912; e += 256) {
        int h = e / 24, q = (e % 24) * 4;
        *(float4*)&Cs[h][q] = *(const float4*)(CF + (size_t)(h0 + h) * NN + j0 + q);
    }
    if (tid < 38) {
        int h = h0 + tid;
        w2s[tid] = (h < HH) ? w2[h] : 0.f;
    }
    __syncthreads();

    float acc[6][6];
    #pragma unroll
    for (int r = 0; r < 6; ++r)
        #pragma unroll
        for (int c = 0; c < 6; ++c) acc[r][c] = 0.f;

    #pragma unroll 2
    for (int h = 0; h < 38; ++h) {
        float wh = w2s[h];
        float4 a03 = *(const float4*)&As[h][4*ty];
        float2 a45 = *(const float2*)&As[h][64 + 2*ty];
        float4 c03 = *(const float4*)&Cs[h][4*tx];
        float2 c45 = *(const float2*)&Cs[h][64 + 2*tx];
        float ar[6] = {a03.x, a03.y, a03.z, a03.w, a45.x, a45.y};
        float cr[6] = {c03.x, c03.y, c03.z, c03.w, c45.x, c45.y};
        #pragma unroll
        for (int r = 0; r < 6; ++r) {
            #pragma unroll
            for (int c = 0; c < 6; ++c) {
                float t = fmaxf(ar[r] + cr[c], 0.f);
                acc[r][c] = fmaf(t, wh, acc[r][c]);
            }
        }
    }

    float* dst = sp + (size_t)p * SP_STR;
    #pragma unroll
    for (int r = 0; r < 6; ++r) {
        int i = (r < 4) ? (i0 + 4*ty + r) : (i0 + 64 + 2*ty + (r - 4));
        float* rp = dst + (size_t)i * NN + j0;
        *(float4*)(rp + 4*tx) =
            make_float4(acc[r][0], acc[r][1], acc[r][2], acc[r][3]);
        *(float2*)(rp + 64 + 2*tx) = make_float2(acc[r][4], acc[r][5]);
    }
}

// ==== K2e: per row: combine 8 partials, exp-rowsum -> esum[row];
//      diagonal j==perm[row] gives t0 (bijection). Plain stores; the
//      dispatch boundary provides cross-XCD visibility (no fences). =========
__global__ __launch_bounds__(256) void k2e_rows(
    const float* __restrict__ wsf, const int* __restrict__ perm,
    const float* __restrict__ b2,
    float* __restrict__ esum, float* __restrict__ t0c)
{
    const int tid = threadIdx.x;
    const float b2v = b2[0];
    const int row = blockIdx.x;
    const int pj = perm[row];          // column holding the matched pair
    const float* spr = wsf + SP_OFF + (size_t)row * NN;
    __shared__ float red[256];

    float e = 0.f;
    #pragma unroll
    for (int jj = 0; jj < 3; ++jj) {
        int j = tid + jj * 256;
        float s = 0.f;
        #pragma unroll
        for (int p = 0; p < 8; ++p) s += spr[(size_t)p * SP_STR + j];
        float u = s + b2v;
        e += expf(u);
        if (j == pj) {                 // exactly one thread matches
            t0c[row] = (u > 0.f) ? u + log1pf(expf(-u)) : log1pf(expf(u));
        }
    }
    red[tid] = e;
    __syncthreads();
    for (int s = 128; s > 0; s >>= 1) {
        if (tid < s) red[tid] += red[tid + s];
        __syncthreads();
    }
    if (tid == 0) esum[row] = red[0];
}

// ================= K3: final double-precision reduction =====================
__global__ __launch_bounds__(256) void k3_final(
    const float* __restrict__ wsf, float* __restrict__ out)
{
    const int tid = threadIdx.x;
    const float* esum = wsf + ES_OFF;
    const float* t0   = wsf + T0_OFF;

    double st0 = 0.0, slse = 0.0;
    for (int i = tid; i < NN; i += 256) {
        st0  += (double)t0[i];
        slse += log((double)NN + (double)esum[i]);
    }
    __shared__ double sa[256], sb[256];
    sa[tid] = st0; sb[tid] = slse;
    __syncthreads();
    for (int s = 128; s > 0; s >>= 1) {
        if (tid < s) { sa[tid] += sa[tid+s]; sb[tid] += sb[tid+s]; }
        __syncthreads();
    }
    if (tid == 0) {
        double lb = sa[0]/(double)NN - (sb[0]/(double)NN - log((double)NN));
        out[0] = (float)lb;
    }
}

extern "C" void kernel_launch(void* const* d_in, const int* in_sizes, int n_in,
                              void* d_out, int out_size, void* d_ws, size_t ws_size,
                              hipStream_t stream) {
    const float* x    = (const float*)d_in[0];
    const float* y    = (const float*)d_in[1];
    const int*   perm = (const int*)  d_in[2];
    const float* W1   = (const float*)d_in[3];
    const float* b1   = (const float*)d_in[4];
    const float* W2   = (const float*)d_in[5];
    const float* b2   = (const float*)d_in[6];
    float* wsf = (float*)d_ws;
    float* out = (float*)d_out;

    k1_gemm    <<<dim3(6,5,16), 256, 0, stream>>>(x, y, perm, W1, wsf);
    k1b_combine<<<480,          256, 0, stream>>>(b1, wsf);
    k2_pair    <<<dim3(8,8,8),  256, 0, stream>>>(wsf, W2, wsf + SP_OFF);
    k2e_rows   <<<NN,           256, 0, stream>>>(wsf, perm, b2,
                                                  wsf + ES_OFF, wsf + T0_OFF);
    k3_final   <<<1,            256, 0, stream>>>(wsf, out);
}